// Round 1
// baseline (207.917 us; speedup 1.0000x reference)
//
#include <hip/hip_runtime.h>

typedef _Float16 f16;
typedef __attribute__((ext_vector_type(8))) _Float16 half8;
typedef __attribute__((ext_vector_type(4))) float v4f;
typedef __attribute__((ext_vector_type(4))) float f32x4v;
typedef __attribute__((ext_vector_type(8))) unsigned short u16x8;

#define NEG_BIG -1e30f

// ---------------------------------------------------------------------------
// Kernel 1: convert queries/keys/values f32 -> f16 (2M elems each)
// ---------------------------------------------------------------------------
__global__ __launch_bounds__(256) void cvt3_kernel(
    const float* __restrict__ q, const float* __restrict__ k, const float* __restrict__ v,
    f16* __restrict__ oq, f16* __restrict__ ok, f16* __restrict__ ov)
{
    int gid = blockIdx.x * 256 + threadIdx.x;     // 0 .. 3*2^19-1, each does 4 elems
    int seg = gid >> 19;                          // 2^19 quads per tensor
    int off = (gid & 524287) << 2;
    const float* src = (seg == 0) ? q : (seg == 1) ? k : v;
    f16* dst = (seg == 0) ? oq : (seg == 1) ? ok : ov;
    f32x4v x = *(const f32x4v*)(src + off);
    union { f16 h[4]; unsigned long long u; } pk;
    pk.h[0] = (f16)x[0]; pk.h[1] = (f16)x[1]; pk.h[2] = (f16)x[2]; pk.h[3] = (f16)x[3];
    *(unsigned long long*)(dst + off) = pk.u;
}

// ---------------------------------------------------------------------------
// Kernel 2: W (1024x1024 f32 row-major) -> W^T (1024x1024 f16 row-major)
// ---------------------------------------------------------------------------
__global__ __launch_bounds__(256) void wtrans_kernel(
    const float* __restrict__ w0, const float* __restrict__ w1,
    const float* __restrict__ w2, const float* __restrict__ w3,
    f16* __restrict__ o0, f16* __restrict__ o1, f16* __restrict__ o2, f16* __restrict__ o3)
{
    __shared__ f16 tile[64][72];
    int zs = blockIdx.z;
    const float* W = (zs == 0) ? w0 : (zs == 1) ? w1 : (zs == 2) ? w2 : w3;
    f16* O = (zs == 0) ? o0 : (zs == 1) ? o1 : (zs == 2) ? o2 : o3;
    int cx = blockIdx.x * 64;    // source col base
    int ry = blockIdx.y * 64;    // source row base
    int tid = threadIdx.x;
    #pragma unroll
    for (int p = 0; p < 4; ++p) {
        int idx = tid + p * 256;
        int r = idx >> 4, c4 = (idx & 15) << 2;
        f32x4v x = *(const f32x4v*)&W[(size_t)(ry + r) * 1024 + cx + c4];
        tile[r][c4 + 0] = (f16)x[0]; tile[r][c4 + 1] = (f16)x[1];
        tile[r][c4 + 2] = (f16)x[2]; tile[r][c4 + 3] = (f16)x[3];
    }
    __syncthreads();
    #pragma unroll
    for (int p = 0; p < 2; ++p) {
        int idx = tid + p * 256;
        int n = idx >> 3, c8 = (idx & 7) << 3;
        union { f16 h[8]; u16x8 u; } pk;
        #pragma unroll
        for (int j = 0; j < 8; ++j) pk.h[j] = tile[c8 + j][n];
        *(u16x8*)&O[(size_t)(cx + n) * 1024 + ry + c8] = pk.u;
    }
}

// ---------------------------------------------------------------------------
// GEMM core: C[m][n] = A[2048x1024] @ Bt[1024x1024]^T + bias[n]
// BM=128 BN=64 BK=64, 256 threads = 4 waves (2 row-halves x 2 col-halves)
// mode 0: store f16 as [b][h][nq][64]   (Q, K)
// mode 1: store f16 as [b][h][64][nq]   (V transposed)
// mode 2: store f32 as [m][n]           (output projection)
// ---------------------------------------------------------------------------
__device__ __forceinline__ void gemm_core(
    const f16* __restrict__ A, const f16* __restrict__ Bt,
    const float* __restrict__ bias, void* __restrict__ out, int mode)
{
    __shared__ f16 As[128 * 72];
    __shared__ f16 Bs[64 * 72];
    const int mbase = blockIdx.y * 128;
    const int nbase = blockIdx.x * 64;
    int tid = threadIdx.x;
    int lane = tid & 63, wave = tid >> 6;
    int ln = lane & 15, hi = lane >> 4;
    int wr = wave & 1, wc = wave >> 1;
    v4f acc[4][2];
    #pragma unroll
    for (int rt = 0; rt < 4; ++rt)
        #pragma unroll
        for (int ct = 0; ct < 2; ++ct) acc[rt][ct] = (v4f){0.f, 0.f, 0.f, 0.f};

    for (int kb = 0; kb < 1024; kb += 64) {
        __syncthreads();
        #pragma unroll
        for (int p = 0; p < 4; ++p) {
            int idx = tid + p * 256;
            int r = idx >> 3, c8 = (idx & 7) << 3;
            *(u16x8*)&As[r * 72 + c8] = *(const u16x8*)&A[(size_t)(mbase + r) * 1024 + kb + c8];
        }
        #pragma unroll
        for (int p = 0; p < 2; ++p) {
            int idx = tid + p * 256;
            int r = idx >> 3, c8 = (idx & 7) << 3;
            *(u16x8*)&Bs[r * 72 + c8] = *(const u16x8*)&Bt[(size_t)(nbase + r) * 1024 + kb + c8];
        }
        __syncthreads();
        #pragma unroll
        for (int kk = 0; kk < 64; kk += 32) {
            half8 aF[4], bF[2];
            #pragma unroll
            for (int rt = 0; rt < 4; ++rt)
                aF[rt] = *(const half8*)&As[(wr * 64 + rt * 16 + ln) * 72 + kk + 8 * hi];
            #pragma unroll
            for (int ct = 0; ct < 2; ++ct)
                bF[ct] = *(const half8*)&Bs[(wc * 32 + ct * 16 + ln) * 72 + kk + 8 * hi];
            #pragma unroll
            for (int rt = 0; rt < 4; ++rt)
                #pragma unroll
                for (int ct = 0; ct < 2; ++ct)
                    acc[rt][ct] = __builtin_amdgcn_mfma_f32_16x16x32_f16(aF[rt], bF[ct], acc[rt][ct], 0, 0, 0);
        }
    }
    #pragma unroll
    for (int rt = 0; rt < 4; ++rt)
      #pragma unroll
      for (int ct = 0; ct < 2; ++ct)
        #pragma unroll
        for (int r = 0; r < 4; ++r) {
            int m = mbase + wr * 64 + rt * 16 + hi * 4 + r;
            int n = nbase + wc * 32 + ct * 16 + ln;
            float val = acc[rt][ct][r] + bias[n];
            if (mode == 0) {
                int bb = m >> 10, nq = m & 1023, hh = n >> 6, d = n & 63;
                ((f16*)out)[(((size_t)(bb * 16 + hh)) * 1024 + nq) * 64 + d] = (f16)val;
            } else if (mode == 1) {
                int bb = m >> 10, nq = m & 1023, hh = n >> 6, d = n & 63;
                ((f16*)out)[(((size_t)(bb * 16 + hh)) * 64 + d) * 1024 + nq] = (f16)val;
            } else {
                ((float*)out)[(size_t)m * 1024 + n] = val;
            }
        }
}

__global__ __launch_bounds__(256) void qkv_gemm_kernel(
    const f16* __restrict__ xq, const f16* __restrict__ xk, const f16* __restrict__ xv,
    const f16* __restrict__ wqt, const f16* __restrict__ wkt, const f16* __restrict__ wvt,
    const float* __restrict__ bq, const float* __restrict__ bk, const float* __restrict__ bv,
    f16* __restrict__ oQ, f16* __restrict__ oK, f16* __restrict__ oVt)
{
    int z = blockIdx.z;
    const f16* A  = (z == 0) ? xq  : (z == 1) ? xk  : xv;
    const f16* B  = (z == 0) ? wqt : (z == 1) ? wkt : wvt;
    const float* bi = (z == 0) ? bq : (z == 1) ? bk : bv;
    void* out = (z == 0) ? (void*)oQ : (z == 1) ? (void*)oK : (void*)oVt;
    gemm_core(A, B, bi, out, (z == 2) ? 1 : 0);
}

__global__ __launch_bounds__(256) void o_gemm_kernel(
    const f16* __restrict__ A, const f16* __restrict__ Wot,
    const float* __restrict__ bo, float* __restrict__ out)
{
    gemm_core(A, Wot, bo, out, 2);
}

// ---------------------------------------------------------------------------
// Attention kernel: one WG = one (b, h, 32-query block)
// phase 1: S = Q K^T * scale -> att_map; z = masked(S * weights) into LDS (f32)
// phase 2: per-row max + sumexp
// phase 3: out = (exp(z-m) @ V) / l  -> hout f16 [b][nq][h*64+d]
// ---------------------------------------------------------------------------
__global__ __launch_bounds__(256) void attn_kernel(
    const f16* __restrict__ Qp, const f16* __restrict__ Kp, const f16* __restrict__ Vt,
    const float* __restrict__ weights, const int* __restrict__ mask,
    float* __restrict__ amap, f16* __restrict__ hout)
{
    __shared__ float zbuf[32][1028];        // 131,584 B (stride 4112 B: 16B-aligned, 2-way banks)
    __shared__ f16 kv[9216];                // K tile [128][72] or V^T tile [64][136]
    __shared__ float row_m[32], row_rl[32];

    int qb = blockIdx.x, h = blockIdx.y, b = blockIdx.z;
    int bh = b * 16 + h;
    const f16* Qb = Qp + ((size_t)bh * 1024 + qb * 32) * 64;
    const f16* Kb = Kp + (size_t)bh * 1024 * 64;
    const f16* Vb = Vt + (size_t)bh * 64 * 1024;
    const float* Wb = weights + ((size_t)bh * 1024 + qb * 32) * 1024;
    const int*   Mb = mask    + ((size_t)bh * 1024 + qb * 32) * 1024;
    float* Ab = amap + ((size_t)bh * 1024 + qb * 32) * 1024;

    int tid = threadIdx.x;
    int lane = tid & 63, wave = tid >> 6;
    int ln = lane & 15, hi = lane >> 4;
    int rg = wave & 1, cg = wave >> 1;

    // Q fragments (16 rows per row-group, d = 0..63), straight from global
    half8 aq0 = *(const half8*)&Qb[(rg * 16 + ln) * 64 + 8 * hi];
    half8 aq1 = *(const half8*)&Qb[(rg * 16 + ln) * 64 + 32 + 8 * hi];

    // ---- phase 1: scores ----
    for (int kt = 0; kt < 8; ++kt) {
        __syncthreads();
        #pragma unroll
        for (int p = 0; p < 4; ++p) {       // stage K tile: 128 k-rows x 64 d
            int idx = tid + p * 256;
            int r = idx >> 3, c8 = (idx & 7) << 3;
            *(u16x8*)&kv[r * 72 + c8] = *(const u16x8*)&Kb[(size_t)(kt * 128 + r) * 64 + c8];
        }
        __syncthreads();
        #pragma unroll
        for (int ct = 0; ct < 4; ++ct) {
            int kcol = cg * 64 + ct * 16 + ln;
            half8 b0 = *(const half8*)&kv[kcol * 72 + 8 * hi];
            half8 b1 = *(const half8*)&kv[kcol * 72 + 32 + 8 * hi];
            v4f acc = (v4f){0.f, 0.f, 0.f, 0.f};
            acc = __builtin_amdgcn_mfma_f32_16x16x32_f16(aq0, b0, acc, 0, 0, 0);
            acc = __builtin_amdgcn_mfma_f32_16x16x32_f16(aq1, b1, acc, 0, 0, 0);
            #pragma unroll
            for (int r = 0; r < 4; ++r) {
                int row = rg * 16 + hi * 4 + r;
                int gcol = kt * 128 + cg * 64 + ct * 16 + ln;
                float s = acc[r] * 0.125f;
                Ab[(size_t)row * 1024 + gcol] = s;
                float wv = Wb[(size_t)row * 1024 + gcol];
                int mk = Mb[(size_t)row * 1024 + gcol];
                zbuf[row][gcol] = (mk == 0) ? NEG_BIG : s * wv;
            }
        }
    }
    __syncthreads();

    // ---- phase 2: row max + sum of exp ----
    #pragma unroll
    for (int r = 0; r < 8; ++r) {
        int row = wave * 8 + r;
        float vals[16];
        float m = -3.0e38f;
        #pragma unroll
        for (int j = 0; j < 16; ++j) { vals[j] = zbuf[row][lane + j * 64]; m = fmaxf(m, vals[j]); }
        #pragma unroll
        for (int s = 32; s >= 1; s >>= 1) m = fmaxf(m, __shfl_xor(m, s, 64));
        float l = 0.f;
        #pragma unroll
        for (int j = 0; j < 16; ++j) l += __expf(vals[j] - m);
        #pragma unroll
        for (int s = 32; s >= 1; s >>= 1) l += __shfl_xor(l, s, 64);
        if (lane == 0) { row_m[row] = m; row_rl[row] = 1.0f / l; }
    }
    __syncthreads();

    // ---- phase 3: PV ----
    v4f acco[2];
    acco[0] = (v4f){0.f, 0.f, 0.f, 0.f};
    acco[1] = (v4f){0.f, 0.f, 0.f, 0.f};
    int zrow = rg * 16 + ln;
    float mrow = row_m[zrow];
    for (int kc = 0; kc < 8; ++kc) {
        __syncthreads();
        #pragma unroll
        for (int p = 0; p < 4; ++p) {       // stage V^T tile: 64 d-rows x 128 k
            int idx = tid + p * 256;
            int r = idx >> 4, c8 = (idx & 15) << 3;
            *(u16x8*)&kv[r * 136 + c8] = *(const u16x8*)&Vb[(size_t)r * 1024 + kc * 128 + c8];
        }
        __syncthreads();
        #pragma unroll
        for (int ks = 0; ks < 4; ++ks) {
            int k0 = kc * 128 + ks * 32 + 8 * hi;
            f32x4v z0 = *(const f32x4v*)&zbuf[zrow][k0];
            f32x4v z1 = *(const f32x4v*)&zbuf[zrow][k0 + 4];
            union { half8 v; f16 hh[8]; } pa;
            pa.hh[0] = (f16)__expf(z0[0] - mrow);
            pa.hh[1] = (f16)__expf(z0[1] - mrow);
            pa.hh[2] = (f16)__expf(z0[2] - mrow);
            pa.hh[3] = (f16)__expf(z0[3] - mrow);
            pa.hh[4] = (f16)__expf(z1[0] - mrow);
            pa.hh[5] = (f16)__expf(z1[1] - mrow);
            pa.hh[6] = (f16)__expf(z1[2] - mrow);
            pa.hh[7] = (f16)__expf(z1[3] - mrow);
            #pragma unroll
            for (int ct = 0; ct < 2; ++ct) {
                int drow = cg * 32 + ct * 16 + ln;
                half8 bv = *(const half8*)&kv[drow * 136 + ks * 32 + 8 * hi];
                acco[ct] = __builtin_amdgcn_mfma_f32_16x16x32_f16(pa.v, bv, acco[ct], 0, 0, 0);
            }
        }
    }
    #pragma unroll
    for (int ct = 0; ct < 2; ++ct)
      #pragma unroll
      for (int r = 0; r < 4; ++r) {
        int row = rg * 16 + hi * 4 + r;
        int d = cg * 32 + ct * 16 + ln;
        float val = acco[ct][r] * row_rl[row];
        hout[((size_t)(b * 1024 + qb * 32 + row)) * 1024 + h * 64 + d] = (f16)val;
    }
}

// ---------------------------------------------------------------------------
extern "C" void kernel_launch(void* const* d_in, const int* in_sizes, int n_in,
                              void* d_out, int out_size, void* d_ws, size_t ws_size,
                              hipStream_t stream)
{
    const float* queries  = (const float*)d_in[0];
    const float* keys     = (const float*)d_in[1];
    const float* values   = (const float*)d_in[2];
    const int*   amask    = (const int*)d_in[3];
    const float* aweights = (const float*)d_in[4];
    const float* Wq = (const float*)d_in[5];  const float* bq = (const float*)d_in[6];
    const float* Wk = (const float*)d_in[7];  const float* bk = (const float*)d_in[8];
    const float* Wv = (const float*)d_in[9];  const float* bv = (const float*)d_in[10];
    const float* Wo = (const float*)d_in[11]; const float* bo = (const float*)d_in[12];

    char* ws = (char*)d_ws;
    const size_t MB = 1024 * 1024;
    f16* q_h  = (f16*)(ws + 0 * MB);
    f16* k_h  = (f16*)(ws + 4 * MB);
    f16* v_h  = (f16*)(ws + 8 * MB);
    f16* wqt  = (f16*)(ws + 12 * MB);
    f16* wkt  = (f16*)(ws + 14 * MB);
    f16* wvt  = (f16*)(ws + 16 * MB);
    f16* wot  = (f16*)(ws + 18 * MB);
    f16* Qp   = (f16*)(ws + 20 * MB);
    f16* Kp   = (f16*)(ws + 24 * MB);
    f16* Vt   = (f16*)(ws + 28 * MB);
    f16* hout = (f16*)(ws + 32 * MB);

    float* out_main = (float*)d_out;
    float* att_map  = out_main + (size_t)2 * 1024 * 1024;

    cvt3_kernel<<<6144, 256, 0, stream>>>(queries, keys, values, q_h, k_h, v_h);
    wtrans_kernel<<<dim3(16, 16, 4), 256, 0, stream>>>(Wq, Wk, Wv, Wo, wqt, wkt, wvt, wot);
    qkv_gemm_kernel<<<dim3(16, 16, 3), 256, 0, stream>>>(q_h, k_h, v_h, wqt, wkt, wvt,
                                                         bq, bk, bv, Qp, Kp, Vt);
    attn_kernel<<<dim3(32, 16, 2), 256, 0, stream>>>(Qp, Kp, Vt, aweights, amask, att_map, hout);
    o_gemm_kernel<<<dim3(16, 16, 1), 256, 0, stream>>>(hout, wot, bo, out_main);
}

// Round 2
// 165.690 us; speedup vs baseline: 1.2549x; 1.2549x over previous
//
#include <hip/hip_runtime.h>

typedef _Float16 f16;
typedef __attribute__((ext_vector_type(4))) _Float16 half4;
typedef __attribute__((ext_vector_type(8))) _Float16 half8;
typedef __attribute__((ext_vector_type(4))) float v4f;
typedef __attribute__((ext_vector_type(4))) float f32x4v;
typedef __attribute__((ext_vector_type(4))) int i32x4;
typedef __attribute__((ext_vector_type(8))) unsigned short u16x8;

#define NEG_BIG -1e30f

#if __has_builtin(__builtin_amdgcn_mfma_f32_16x16x16_f16)
#define MFMA16(a, b, c) __builtin_amdgcn_mfma_f32_16x16x16_f16(a, b, c, 0, 0, 0)
#else
#define MFMA16(a, b, c) __builtin_amdgcn_mfma_f32_16x16x16f16(a, b, c, 0, 0, 0)
#endif

// ---------------------------------------------------------------------------
// Kernel 1: convert queries/keys/values f32 -> f16 (2M elems each)
// ---------------------------------------------------------------------------
__global__ __launch_bounds__(256) void cvt3_kernel(
    const float* __restrict__ q, const float* __restrict__ k, const float* __restrict__ v,
    f16* __restrict__ oq, f16* __restrict__ ok, f16* __restrict__ ov)
{
    int gid = blockIdx.x * 256 + threadIdx.x;
    int seg = gid >> 19;
    int off = (gid & 524287) << 2;
    const float* src = (seg == 0) ? q : (seg == 1) ? k : v;
    f16* dst = (seg == 0) ? oq : (seg == 1) ? ok : ov;
    f32x4v x = *(const f32x4v*)(src + off);
    union { f16 h[4]; unsigned long long u; } pk;
    pk.h[0] = (f16)x[0]; pk.h[1] = (f16)x[1]; pk.h[2] = (f16)x[2]; pk.h[3] = (f16)x[3];
    *(unsigned long long*)(dst + off) = pk.u;
}

// ---------------------------------------------------------------------------
// Kernel 2: W (1024x1024 f32 row-major) -> W^T (1024x1024 f16 row-major)
// ---------------------------------------------------------------------------
__global__ __launch_bounds__(256) void wtrans_kernel(
    const float* __restrict__ w0, const float* __restrict__ w1,
    const float* __restrict__ w2, const float* __restrict__ w3,
    f16* __restrict__ o0, f16* __restrict__ o1, f16* __restrict__ o2, f16* __restrict__ o3)
{
    __shared__ f16 tile[64][72];
    int zs = blockIdx.z;
    const float* W = (zs == 0) ? w0 : (zs == 1) ? w1 : (zs == 2) ? w2 : w3;
    f16* O = (zs == 0) ? o0 : (zs == 1) ? o1 : (zs == 2) ? o2 : o3;
    int cx = blockIdx.x * 64;
    int ry = blockIdx.y * 64;
    int tid = threadIdx.x;
    #pragma unroll
    for (int p = 0; p < 4; ++p) {
        int idx = tid + p * 256;
        int r = idx >> 4, c4 = (idx & 15) << 2;
        f32x4v x = *(const f32x4v*)&W[(size_t)(ry + r) * 1024 + cx + c4];
        tile[r][c4 + 0] = (f16)x[0]; tile[r][c4 + 1] = (f16)x[1];
        tile[r][c4 + 2] = (f16)x[2]; tile[r][c4 + 3] = (f16)x[3];
    }
    __syncthreads();
    #pragma unroll
    for (int p = 0; p < 2; ++p) {
        int idx = tid + p * 256;
        int n = idx >> 3, c8 = (idx & 7) << 3;
        union { f16 h[8]; u16x8 u; } pk;
        #pragma unroll
        for (int j = 0; j < 8; ++j) pk.h[j] = tile[c8 + j][n];
        *(u16x8*)&O[(size_t)(cx + n) * 1024 + ry + c8] = pk.u;
    }
}

// ---------------------------------------------------------------------------
// GEMM core: C[m][n] = A[2048x1024] @ Bt[1024x1024]^T + bias[n]
// ---------------------------------------------------------------------------
__device__ __forceinline__ void gemm_core(
    const f16* __restrict__ A, const f16* __restrict__ Bt,
    const float* __restrict__ bias, void* __restrict__ out, int mode)
{
    __shared__ f16 As[128 * 72];
    __shared__ f16 Bs[64 * 72];
    const int mbase = blockIdx.y * 128;
    const int nbase = blockIdx.x * 64;
    int tid = threadIdx.x;
    int lane = tid & 63, wave = tid >> 6;
    int ln = lane & 15, hi = lane >> 4;
    int wr = wave & 1, wc = wave >> 1;
    v4f acc[4][2];
    #pragma unroll
    for (int rt = 0; rt < 4; ++rt)
        #pragma unroll
        for (int ct = 0; ct < 2; ++ct) acc[rt][ct] = (v4f){0.f, 0.f, 0.f, 0.f};

    for (int kb = 0; kb < 1024; kb += 64) {
        __syncthreads();
        #pragma unroll
        for (int p = 0; p < 4; ++p) {
            int idx = tid + p * 256;
            int r = idx >> 3, c8 = (idx & 7) << 3;
            *(u16x8*)&As[r * 72 + c8] = *(const u16x8*)&A[(size_t)(mbase + r) * 1024 + kb + c8];
        }
        #pragma unroll
        for (int p = 0; p < 2; ++p) {
            int idx = tid + p * 256;
            int r = idx >> 3, c8 = (idx & 7) << 3;
            *(u16x8*)&Bs[r * 72 + c8] = *(const u16x8*)&Bt[(size_t)(nbase + r) * 1024 + kb + c8];
        }
        __syncthreads();
        #pragma unroll
        for (int kk = 0; kk < 64; kk += 32) {
            half8 aF[4], bF[2];
            #pragma unroll
            for (int rt = 0; rt < 4; ++rt)
                aF[rt] = *(const half8*)&As[(wr * 64 + rt * 16 + ln) * 72 + kk + 8 * hi];
            #pragma unroll
            for (int ct = 0; ct < 2; ++ct)
                bF[ct] = *(const half8*)&Bs[(wc * 32 + ct * 16 + ln) * 72 + kk + 8 * hi];
            #pragma unroll
            for (int rt = 0; rt < 4; ++rt)
                #pragma unroll
                for (int ct = 0; ct < 2; ++ct)
                    acc[rt][ct] = __builtin_amdgcn_mfma_f32_16x16x32_f16(aF[rt], bF[ct], acc[rt][ct], 0, 0, 0);
        }
    }
    #pragma unroll
    for (int rt = 0; rt < 4; ++rt)
      #pragma unroll
      for (int ct = 0; ct < 2; ++ct)
        #pragma unroll
        for (int r = 0; r < 4; ++r) {
            int m = mbase + wr * 64 + rt * 16 + hi * 4 + r;
            int n = nbase + wc * 32 + ct * 16 + ln;
            float val = acc[rt][ct][r] + bias[n];
            if (mode == 0) {
                int bb = m >> 10, nq = m & 1023, hh = n >> 6, d = n & 63;
                ((f16*)out)[(((size_t)(bb * 16 + hh)) * 1024 + nq) * 64 + d] = (f16)val;
            } else if (mode == 1) {
                int bb = m >> 10, nq = m & 1023, hh = n >> 6, d = n & 63;
                ((f16*)out)[(((size_t)(bb * 16 + hh)) * 64 + d) * 1024 + nq] = (f16)val;
            } else {
                ((float*)out)[(size_t)m * 1024 + n] = val;
            }
        }
}

__global__ __launch_bounds__(256) void qkv_gemm_kernel(
    const f16* __restrict__ xq, const f16* __restrict__ xk, const f16* __restrict__ xv,
    const f16* __restrict__ wqt, const f16* __restrict__ wkt, const f16* __restrict__ wvt,
    const float* __restrict__ bq, const float* __restrict__ bk, const float* __restrict__ bv,
    f16* __restrict__ oQ, f16* __restrict__ oK, f16* __restrict__ oVt)
{
    int z = blockIdx.z;
    const f16* A  = (z == 0) ? xq  : (z == 1) ? xk  : xv;
    const f16* B  = (z == 0) ? wqt : (z == 1) ? wkt : wvt;
    const float* bi = (z == 0) ? bq : (z == 1) ? bk : bv;
    void* out = (z == 0) ? (void*)oQ : (z == 1) ? (void*)oK : (void*)oVt;
    gemm_core(A, B, bi, out, (z == 2) ? 1 : 0);
}

__global__ __launch_bounds__(256) void o_gemm_kernel(
    const f16* __restrict__ A, const f16* __restrict__ Wot,
    const float* __restrict__ bo, float* __restrict__ out)
{
    gemm_core(A, Wot, bo, out, 2);
}

// ---------------------------------------------------------------------------
// Flash-style attention, swapped-operand layout.
// WG = 256 threads = 4 waves; each wave owns 16 q-rows (q = lane&15).
// Per k-tile of 64 keys:
//   S^T = mfma(K-frag, Q-frag)  -> lane holds S^T[key=t*16+4*hi+r][q=ln]
//   amap store (vec4), z = mask ? s*w : -1e30, online softmax (lane-local
//   + 2 shfl_xor), P^T stays in regs as K=16 MFMA B-fragments,
//   O^T += mfma(V^T-frag, P^T-frag)  (16x16x16).
// K/V tiles double-buffered in LDS (36 KB); weights/mask prefetched 1 tile.
// ---------------------------------------------------------------------------
__global__ __launch_bounds__(256) void attn_kernel(
    const f16* __restrict__ Qp, const f16* __restrict__ Kp, const f16* __restrict__ Vt,
    const float* __restrict__ weights, const int* __restrict__ mask,
    float* __restrict__ amap, f16* __restrict__ hout)
{
    __shared__ f16 Ks[2][64 * 72];
    __shared__ f16 Vs[2][64 * 72];

    int qb = blockIdx.x, h = blockIdx.y, b = blockIdx.z;
    int bh = b * 16 + h;
    int tid = threadIdx.x;
    int lane = tid & 63, wave = tid >> 6;
    int ln = lane & 15, hi = lane >> 4;

    const f16* Kb = Kp + (size_t)bh * 1024 * 64;
    const f16* Vb = Vt + (size_t)bh * 64 * 1024;
    int qg = qb * 64 + wave * 16 + ln;                  // this lane's q row
    const f16*  Qb = Qp + ((size_t)bh * 1024 + qg) * 64;
    const float* Wr = weights + ((size_t)bh * 1024 + qg) * 1024;
    const int*   Mr = mask    + ((size_t)bh * 1024 + qg) * 1024;
    float*       Ar = amap    + ((size_t)bh * 1024 + qg) * 1024;

    // Q B-fragments (d-chunks 0..31, 32..63)
    half8 qf0 = *(const half8*)&Qb[8 * hi];
    half8 qf1 = *(const half8*)&Qb[32 + 8 * hi];

    // cooperative staging coords: each thread stages 16 f16 of K and of V^T
    int srow = tid >> 2, sc = (tid & 3) * 16;

    // ---- prologue: stage tile 0, load w/mask for tile 0 ----
    {
        const f16* kg = Kb + (size_t)srow * 64 + sc;
        const f16* vg = Vb + (size_t)srow * 1024 + sc;
        half8 k0v = *(const half8*)&kg[0];
        half8 k1v = *(const half8*)&kg[8];
        half8 v0v = *(const half8*)&vg[0];
        half8 v1v = *(const half8*)&vg[8];
        *(half8*)&Ks[0][srow * 72 + sc]     = k0v;
        *(half8*)&Ks[0][srow * 72 + sc + 8] = k1v;
        *(half8*)&Vs[0][srow * 72 + sc]     = v0v;
        *(half8*)&Vs[0][srow * 72 + sc + 8] = v1v;
    }
    f32x4v wcur[4]; i32x4 mcur[4];
    #pragma unroll
    for (int t = 0; t < 4; ++t) {
        wcur[t] = *(const f32x4v*)&Wr[t * 16 + 4 * hi];
        mcur[t] = *(const i32x4*)&Mr[t * 16 + 4 * hi];
    }
    __syncthreads();

    float mrun = -3.0e38f, lrun = 0.f;
    v4f oacc[4];
    #pragma unroll
    for (int dt = 0; dt < 4; ++dt) oacc[dt] = (v4f){0.f, 0.f, 0.f, 0.f};

    for (int kt = 0; kt < 16; ++kt) {
        int buf = kt & 1;
        int k0n = (kt + 1) * 64;

        // issue next K/V tile global loads
        half8 nk0, nk1, nv0, nv1;
        if (kt < 15) {
            const f16* kg = Kb + (size_t)(k0n + srow) * 64 + sc;
            const f16* vg = Vb + (size_t)srow * 1024 + k0n + sc;
            nk0 = *(const half8*)&kg[0];
            nk1 = *(const half8*)&kg[8];
            nv0 = *(const half8*)&vg[0];
            nv1 = *(const half8*)&vg[8];
        }
        // prefetch next weights/mask
        f32x4v wnxt[4]; i32x4 mnxt[4];
        if (kt < 15) {
            #pragma unroll
            for (int t = 0; t < 4; ++t) {
                wnxt[t] = *(const f32x4v*)&Wr[k0n + t * 16 + 4 * hi];
                mnxt[t] = *(const i32x4*)&Mr[k0n + t * 16 + 4 * hi];
            }
        }

        // ---- S^T = K Q^T for this tile ----
        v4f st[4];
        #pragma unroll
        for (int t = 0; t < 4; ++t) {
            half8 ka = *(const half8*)&Ks[buf][(t * 16 + ln) * 72 + 8 * hi];
            half8 kb2 = *(const half8*)&Ks[buf][(t * 16 + ln) * 72 + 32 + 8 * hi];
            v4f a = (v4f){0.f, 0.f, 0.f, 0.f};
            a = __builtin_amdgcn_mfma_f32_16x16x32_f16(ka, qf0, a, 0, 0, 0);
            a = __builtin_amdgcn_mfma_f32_16x16x32_f16(kb2, qf1, a, 0, 0, 0);
            st[t] = a;
        }

        // ---- amap store + z ----
        float z[4][4];
        #pragma unroll
        for (int t = 0; t < 4; ++t) {
            f32x4v sv = st[t] * 0.125f;
            *(f32x4v*)&Ar[kt * 64 + t * 16 + 4 * hi] = sv;
            #pragma unroll
            for (int r = 0; r < 4; ++r)
                z[t][r] = (mcur[t][r] == 0) ? NEG_BIG : sv[r] * wcur[t][r];
        }

        // ---- online softmax (q = ln is lane-local; reduce across hi groups) ----
        float tm = z[0][0];
        #pragma unroll
        for (int t = 0; t < 4; ++t)
            #pragma unroll
            for (int r = 0; r < 4; ++r) tm = fmaxf(tm, z[t][r]);
        tm = fmaxf(tm, __shfl_xor(tm, 16, 64));
        tm = fmaxf(tm, __shfl_xor(tm, 32, 64));
        float mnew = fmaxf(mrun, tm);
        float fsc = __expf(mrun - mnew);
        float p[4][4];
        float tsum = 0.f;
        #pragma unroll
        for (int t = 0; t < 4; ++t)
            #pragma unroll
            for (int r = 0; r < 4; ++r) { p[t][r] = __expf(z[t][r] - mnew); tsum += p[t][r]; }
        tsum += __shfl_xor(tsum, 16, 64);
        tsum += __shfl_xor(tsum, 32, 64);
        lrun = lrun * fsc + tsum;
        mrun = mnew;
        #pragma unroll
        for (int dt = 0; dt < 4; ++dt) oacc[dt] *= fsc;

        // ---- P^T -> f16 B-fragments (K=16 layout: k = 4*hi + j) ----
        half4 pf[4];
        #pragma unroll
        for (int t = 0; t < 4; ++t) {
            half4 v;
            v[0] = (f16)p[t][0]; v[1] = (f16)p[t][1];
            v[2] = (f16)p[t][2]; v[3] = (f16)p[t][3];
            pf[t] = v;
        }

        // ---- O^T += V^T P^T ----
        #pragma unroll
        for (int t = 0; t < 4; ++t)
            #pragma unroll
            for (int dt = 0; dt < 4; ++dt) {
                half4 vf = *(const half4*)&Vs[buf][(dt * 16 + ln) * 72 + t * 16 + 4 * hi];
                oacc[dt] = MFMA16(vf, pf[t], oacc[dt]);
            }

        // ---- write staged tile, rotate prefetch ----
        if (kt < 15) {
            *(half8*)&Ks[buf ^ 1][srow * 72 + sc]     = nk0;
            *(half8*)&Ks[buf ^ 1][srow * 72 + sc + 8] = nk1;
            *(half8*)&Vs[buf ^ 1][srow * 72 + sc]     = nv0;
            *(half8*)&Vs[buf ^ 1][srow * 72 + sc + 8] = nv1;
            #pragma unroll
            for (int t = 0; t < 4; ++t) { wcur[t] = wnxt[t]; mcur[t] = mnxt[t]; }
        }
        __syncthreads();
    }

    // ---- epilogue: normalize, store O^T lane slice (q=ln, d=dt*16+4*hi+r) ----
    float rl = 1.0f / lrun;
    #pragma unroll
    for (int dt = 0; dt < 4; ++dt) {
        half4 ov;
        #pragma unroll
        for (int r = 0; r < 4; ++r) ov[r] = (f16)(oacc[dt][r] * rl);
        *(half4*)&hout[((size_t)(b * 1024 + qg)) * 1024 + h * 64 + dt * 16 + 4 * hi] = ov;
    }
}

// ---------------------------------------------------------------------------
extern "C" void kernel_launch(void* const* d_in, const int* in_sizes, int n_in,
                              void* d_out, int out_size, void* d_ws, size_t ws_size,
                              hipStream_t stream)
{
    const float* queries  = (const float*)d_in[0];
    const float* keys     = (const float*)d_in[1];
    const float* values   = (const float*)d_in[2];
    const int*   amask    = (const int*)d_in[3];
    const float* aweights = (const float*)d_in[4];
    const float* Wq = (const float*)d_in[5];  const float* bq = (const float*)d_in[6];
    const float* Wk = (const float*)d_in[7];  const float* bk = (const float*)d_in[8];
    const float* Wv = (const float*)d_in[9];  const float* bv = (const float*)d_in[10];
    const float* Wo = (const float*)d_in[11]; const float* bo = (const float*)d_in[12];

    char* ws = (char*)d_ws;
    const size_t MB = 1024 * 1024;
    f16* q_h  = (f16*)(ws + 0 * MB);
    f16* k_h  = (f16*)(ws + 4 * MB);
    f16* v_h  = (f16*)(ws + 8 * MB);
    f16* wqt  = (f16*)(ws + 12 * MB);
    f16* wkt  = (f16*)(ws + 14 * MB);
    f16* wvt  = (f16*)(ws + 16 * MB);
    f16* wot  = (f16*)(ws + 18 * MB);
    f16* Qp   = (f16*)(ws + 20 * MB);
    f16* Kp   = (f16*)(ws + 24 * MB);
    f16* Vt   = (f16*)(ws + 28 * MB);
    f16* hout = (f16*)(ws + 32 * MB);

    float* out_main = (float*)d_out;
    float* att_map  = out_main + (size_t)2 * 1024 * 1024;

    cvt3_kernel<<<6144, 256, 0, stream>>>(queries, keys, values, q_h, k_h, v_h);
    wtrans_kernel<<<dim3(16, 16, 4), 256, 0, stream>>>(Wq, Wk, Wv, Wo, wqt, wkt, wvt, wot);
    qkv_gemm_kernel<<<dim3(16, 16, 3), 256, 0, stream>>>(q_h, k_h, v_h, wqt, wkt, wvt,
                                                         bq, bk, bv, Qp, Kp, Vt);
    attn_kernel<<<dim3(16, 16, 2), 256, 0, stream>>>(Qp, Kp, Vt, aweights, amask, att_map, hout);
    o_gemm_kernel<<<dim3(16, 16, 1), 256, 0, stream>>>(hout, wot, bo, out_main);
}